// Round 2
// baseline (581.869 us; speedup 1.0000x reference)
//
#include <hip/hip_runtime.h>

#define BB 4
#define SS 1024
#define DD 512
#define HH 16
#define DH 32

typedef __attribute__((ext_vector_type(8))) short bf16x8;
typedef __attribute__((ext_vector_type(4))) float f32x4;

__device__ __forceinline__ short f2bf(float x) {
    union { float f; unsigned u; } v; v.f = x;
    unsigned r = (v.u + 0x7FFFu + ((v.u >> 16) & 1u)) >> 16;
    return (short)r;
}
__device__ __forceinline__ float bf2f(unsigned short u) {
    union { unsigned u; float f; } v; v.u = ((unsigned)u) << 16;
    return v.f;
}
__device__ __forceinline__ void gl_lds16(const void* g, void* l) {
    __builtin_amdgcn_global_load_lds(
        (const __attribute__((address_space(1))) unsigned int*)g,
        (__attribute__((address_space(3))) unsigned int*)l, 16, 0, 0);
}

// ---------------------------------------------------------------------------
// Mask normalization: detect byte-bool vs int32 layout, expand to int[4096].
// ---------------------------------------------------------------------------
__global__ void mask_prep_kernel(const unsigned char* __restrict__ raw,
                                 int* __restrict__ norm) {
    __shared__ int bad;
    if (threadIdx.x == 0) bad = 0;
    __syncthreads();
    const unsigned int* w = (const unsigned int*)raw;
    int isbad = 0;
    for (int i = threadIdx.x; i < 1024; i += 256)
        if (w[i] > 1u) isbad = 1;
    if (isbad) atomicOr(&bad, 1);
    __syncthreads();
    if (bad) {
        for (int i = threadIdx.x; i < BB * SS; i += 256)
            norm[i] = raw[i] != 0;
    } else {
        const int* wi = (const int*)raw;
        for (int i = threadIdx.x; i < BB * SS; i += 256)
            norm[i] = wi[i] != 0;
    }
}

// ---------------------------------------------------------------------------
// Elementwise fp32 -> bf16 convert (n4 = number of float4 groups)
// ---------------------------------------------------------------------------
__global__ __launch_bounds__(256) void conv_kernel(
    const float* __restrict__ x, unsigned short* __restrict__ y, int n4) {
    int i = blockIdx.x * 256 + threadIdx.x;
    if (i < n4) {
        float4 v = ((const float4*)x)[i];
        ushort4 o;
        o.x = (unsigned short)f2bf(v.x); o.y = (unsigned short)f2bf(v.y);
        o.z = (unsigned short)f2bf(v.z); o.w = (unsigned short)f2bf(v.w);
        ((ushort4*)y)[i] = o;
    }
}

// ---------------------------------------------------------------------------
// 512x512 transpose + convert: WT[n][k] = bf16(W[k][n])
// ---------------------------------------------------------------------------
__global__ __launch_bounds__(256) void tconv_kernel(
    const float* __restrict__ W, unsigned short* __restrict__ WT) {
    __shared__ float t[64][68];
    const int bx = blockIdx.x * 64, by = blockIdx.y * 64;
    const int tid = threadIdx.x;
    const int r = tid >> 4, c4 = (tid & 15) * 4;
#pragma unroll
    for (int i = 0; i < 4; ++i) {
        float4 v = *(const float4*)(W + (size_t)(bx + r + i * 16) * 512 + by + c4);
        t[r + i * 16][c4 + 0] = v.x; t[r + i * 16][c4 + 1] = v.y;
        t[r + i * 16][c4 + 2] = v.z; t[r + i * 16][c4 + 3] = v.w;
    }
    __syncthreads();
#pragma unroll
    for (int i = 0; i < 4; ++i) {
        int c = r + i * 16;
        ushort4 o;
        o.x = (unsigned short)f2bf(t[c4 + 0][c]);
        o.y = (unsigned short)f2bf(t[c4 + 1][c]);
        o.z = (unsigned short)f2bf(t[c4 + 2][c]);
        o.w = (unsigned short)f2bf(t[c4 + 3][c]);
        *(ushort4*)(WT + (size_t)(by + c) * 512 + bx + c4) = o;
    }
}

// ---------------------------------------------------------------------------
// bf16 MFMA GEMM: C[M x N] = A[M x 512] @ BT[N x 512]^T
// 128x128 tile, BK=64, global_load_lds staging with XOR slot swizzle
// (conflict-free ds_read_b128 fragments). MODE 0: fp32 out + bias;
// MODE 1: bf16 out row-major; MODE 2: bf16 out in vT[b][h][dh][s] layout.
// ---------------------------------------------------------------------------
template <int MODE>
__global__ __launch_bounds__(256) void gemm_mfma_kernel(
    const unsigned short* __restrict__ A, const unsigned short* __restrict__ BT,
    const float* __restrict__ bias, void* __restrict__ Cout, int N) {
    __shared__ unsigned short As[128 * 64];
    __shared__ unsigned short Bs[128 * 64];
    const int tid = threadIdx.x;
    const int w = tid >> 6, lane = tid & 63;
    const int wm = w >> 1, wn = w & 1;
    const int ln = lane & 15, quad = lane >> 4;
    const int m0 = blockIdx.x * 128, n0 = blockIdx.y * 128;
    f32x4 acc[4][4] = {};
    for (int k0 = 0; k0 < 512; k0 += 64) {
        __syncthreads();
#pragma unroll
        for (int i = 0; i < 4; ++i) {
            int slot = i * 256 + tid;
            int row = slot >> 3, sl = slot & 7;
            int gsl = sl ^ (row & 7);
            gl_lds16(A + (size_t)(m0 + row) * 512 + k0 + gsl * 8, As + slot * 8);
            gl_lds16(BT + (size_t)(n0 + row) * 512 + k0 + gsl * 8, Bs + slot * 8);
        }
        __syncthreads();
#pragma unroll
        for (int kc = 0; kc < 2; ++kc) {
            bf16x8 af[4], bfr[4];
#pragma unroll
            for (int mt = 0; mt < 4; ++mt) {
                int row = wm * 64 + mt * 16 + ln;
                int sl = (kc * 4 + quad) ^ (row & 7);
                af[mt] = *(const bf16x8*)(As + row * 64 + sl * 8);
            }
#pragma unroll
            for (int nt = 0; nt < 4; ++nt) {
                int row = wn * 64 + nt * 16 + ln;
                int sl = (kc * 4 + quad) ^ (row & 7);
                bfr[nt] = *(const bf16x8*)(Bs + row * 64 + sl * 8);
            }
#pragma unroll
            for (int mt = 0; mt < 4; ++mt)
#pragma unroll
                for (int nt = 0; nt < 4; ++nt)
                    acc[mt][nt] = __builtin_amdgcn_mfma_f32_16x16x32_bf16(
                        af[mt], bfr[nt], acc[mt][nt], 0, 0, 0);
        }
    }
#pragma unroll
    for (int mt = 0; mt < 4; ++mt) {
#pragma unroll
        for (int nt = 0; nt < 4; ++nt) {
            int col = n0 + wn * 64 + nt * 16 + ln;
#pragma unroll
            for (int r = 0; r < 4; ++r) {
                int row = m0 + wm * 64 + mt * 16 + quad * 4 + r;
                float v = acc[mt][nt][r];
                if (MODE == 0) {
                    ((float*)Cout)[(size_t)row * N + col] = v + bias[col];
                } else if (MODE == 1) {
                    ((unsigned short*)Cout)[(size_t)row * N + col] =
                        (unsigned short)f2bf(v);
                } else {
                    int hh = row >> 5, dh = row & 31;
                    int bb = col >> 10, si = col & 1023;
                    ((unsigned short*)Cout)[(((size_t)(bb * HH + hh) * 32 + dh) << 10) + si] =
                        (unsigned short)f2bf(v);
                }
            }
        }
    }
}

// ---------------------------------------------------------------------------
// Fused attention, register-resident scores with SWAPPED MFMA operands:
//   scores computed as S^T tiles: mfma(K_frag, Q_frag) -> each lane holds ONE
//   q-row (q-local = ln) and 4 consecutive k-columns (quad*4+r) per tile.
//   -> float4 coalesced attn stores (no shuffles), b64 LDS writes,
//      2-step row reductions. pos staging aliases sbf (dead before sbf use).
// LDS ~33.8 KB -> 4 blocks/CU.
// ---------------------------------------------------------------------------
__global__ __launch_bounds__(256, 4) void fused_attn_kernel(
    const float* __restrict__ qp, const unsigned short* __restrict__ kp,
    const unsigned short* __restrict__ pp, const unsigned short* __restrict__ vT,
    const float* __restrict__ ub, const float* __restrict__ vb,
    const int* __restrict__ mask, float* __restrict__ attn,
    float* __restrict__ ctx) {
    const int b = blockIdx.z, h = blockIdx.y, q0 = blockIdx.x * 16;
    const int tid = threadIdx.x;
    const int w = tid >> 6, lane = tid & 63;
    const int ln = lane & 15, quad = lane >> 4;

    // sbf rows stride 1032 ushorts (=2064B): keeps 16B alignment for b128
    // reads and the near-conflict-free phase-3 read pattern.
    __shared__ __align__(16) unsigned short sbf[16][1032];
    __shared__ float rowred[2][4][16];
    __shared__ float invLDS[16];

    // per-wave pos staging region: posb[which (2)][q=16][88] ushort, carved
    // from sbf (pos is dead before any sbf e-value is written).
    unsigned short* posb = &sbf[0][0] + w * 2816;

    // ---- phase 1: S^T score tiles into registers ----
    bf16x8 a_c, a_pA, a_pB;
    {
        const float* qrow = qp + ((size_t)(b * SS + q0 + ln)) * DD + h * DH + quad * 8;
        const int qrB = q0 + ln + 1;
        const float* qrowB = qp + ((size_t)(b * SS + qrB)) * DD + h * DH + quad * 8;
#pragma unroll
        for (int j = 0; j < 8; ++j) {
            float uu = ub[h * DH + quad * 8 + j];
            float vv = vb[h * DH + quad * 8 + j];
            float qv = qrow[j];
            a_c[j] = f2bf(qv + uu);
            a_pA[j] = f2bf(qv + vv);
            a_pB[j] = (qrB < SS) ? f2bf(qrowB[j] + vv) : (short)0;
        }
    }
    const unsigned short* pbase = pp + h * DH + quad * 8;
    const int kw = w * 256;
    f32x4 acc_s[16];
#pragma unroll
    for (int c = 0; c < 4; ++c) {
        const int k0 = kw + c * 64;
        const bool needA = (k0 <= q0 + 15);
        const bool needB = (k0 + 63 >= q0 + 1);
        if (needA) {
            const int jA0 = k0 - q0 + SS - 16;
#pragma unroll
            for (int t = 0; t < 5; ++t) {
                int j = jA0 + t * 16 + ln;
                bf16x8 bp;
                if ((unsigned)j < (unsigned)SS) {
                    bp = *(const bf16x8*)(pbase + (size_t)j * DD);
                } else {
#pragma unroll
                    for (int jj = 0; jj < 8; ++jj) bp[jj] = (short)0;
                }
                f32x4 acc = {0.f, 0.f, 0.f, 0.f};
                // swapped: rows = p-window idx, cols = q
                acc = __builtin_amdgcn_mfma_f32_16x16x32_bf16(bp, a_pA, acc, 0, 0, 0);
                ushort4 o;
                o.x = (unsigned short)f2bf(acc[0]);
                o.y = (unsigned short)f2bf(acc[1]);
                o.z = (unsigned short)f2bf(acc[2]);
                o.w = (unsigned short)f2bf(acc[3]);
                *(ushort4*)(posb + ln * 88 + t * 16 + quad * 4) = o;
            }
        }
        if (needB) {
            const int jB0 = k0 - q0 - 17;
#pragma unroll
            for (int t = 0; t < 5; ++t) {
                int j = jB0 + t * 16 + ln;
                bf16x8 bp;
                if ((unsigned)j < (unsigned)SS) {
                    bp = *(const bf16x8*)(pbase + (size_t)j * DD);
                } else {
#pragma unroll
                    for (int jj = 0; jj < 8; ++jj) bp[jj] = (short)0;
                }
                f32x4 acc = {0.f, 0.f, 0.f, 0.f};
                acc = __builtin_amdgcn_mfma_f32_16x16x32_bf16(bp, a_pB, acc, 0, 0, 0);
                ushort4 o;
                o.x = (unsigned short)f2bf(acc[0]);
                o.y = (unsigned short)f2bf(acc[1]);
                o.z = (unsigned short)f2bf(acc[2]);
                o.w = (unsigned short)f2bf(acc[3]);
                *(ushort4*)(posb + 1408 + ln * 88 + t * 16 + quad * 4) = o;
            }
        }
        asm volatile("s_waitcnt lgkmcnt(0)" ::: "memory");
#pragma unroll
        for (int t = 0; t < 4; ++t) {
            const int kk0 = k0 + t * 16;
            bf16x8 bk = *(const bf16x8*)(
                kp + ((size_t)(b * SS + kk0 + ln)) * DD + h * DH + quad * 8);
            f32x4 acc = {0.f, 0.f, 0.f, 0.f};
            // swapped: rows = k, cols = q (lane ln owns q-row q0+ln)
            acc = __builtin_amdgcn_mfma_f32_16x16x32_bf16(bk, a_c, acc, 0, 0, 0);
#pragma unroll
            for (int r = 0; r < 4; ++r) {
                const int kkl = t * 16 + quad * 4 + r;
                const int which = (k0 + kkl <= q0 + ln) ? 0 : 1;
                acc[r] += bf2f(posb[which * 1408 + ln * 88 + (kkl - ln + 15)]);
            }
            acc_s[c * 4 + t] = acc;
        }
    }

    // ---- phase 2: softmax (row = ln, lane-local) ----
    const float scale = 0.04419417382415922f;   // 1/sqrt(512)
    const int* mrow = mask + ((size_t)b << 10);
    float mx = -3.4e38f;
#pragma unroll
    for (int tt = 0; tt < 16; ++tt) {
        int col = kw + tt * 16 + quad * 4;
        int4 mm = *(const int4*)(mrow + col);
        float v0 = mm.x ? -1e9f : acc_s[tt][0] * scale;
        float v1 = mm.y ? -1e9f : acc_s[tt][1] * scale;
        float v2 = mm.z ? -1e9f : acc_s[tt][2] * scale;
        float v3 = mm.w ? -1e9f : acc_s[tt][3] * scale;
        acc_s[tt][0] = v0; acc_s[tt][1] = v1;
        acc_s[tt][2] = v2; acc_s[tt][3] = v3;
        mx = fmaxf(mx, fmaxf(fmaxf(v0, v1), fmaxf(v2, v3)));
    }
    mx = fmaxf(mx, __shfl_xor(mx, 16, 64));
    mx = fmaxf(mx, __shfl_xor(mx, 32, 64));
    if (quad == 0) rowred[0][w][ln] = mx;
    __syncthreads();   // also: all waves past phase 1 (posb dead from here)
    float gm = fmaxf(fmaxf(rowred[0][0][ln], rowred[0][1][ln]),
                     fmaxf(rowred[0][2][ln], rowred[0][3][ln]));
    float sm = 0.f;
#pragma unroll
    for (int tt = 0; tt < 16; ++tt) {
#pragma unroll
        for (int r = 0; r < 4; ++r) {
            float e = __expf(acc_s[tt][r] - gm);
            acc_s[tt][r] = e;
            sm += e;
        }
    }
    sm += __shfl_xor(sm, 16, 64);
    sm += __shfl_xor(sm, 32, 64);
    if (quad == 0) rowred[1][w][ln] = sm;
    __syncthreads();
    float l = rowred[1][0][ln] + rowred[1][1][ln] +
              rowred[1][2][ln] + rowred[1][3][ln];
    float inv = 1.f / l;
    if (w == 0 && quad == 0) invLDS[ln] = inv;
    // write unnormalized e -> sbf (own cols only: no barrier needed before
    // phase 3), attn -> global as coalesced float4 full-line stores.
    float* arow = attn + (((size_t)(b * HH + h)) << 20) + (size_t)(q0 + ln) * SS;
#pragma unroll
    for (int tt = 0; tt < 16; ++tt) {
        int col = kw + tt * 16 + quad * 4;
        ushort4 eo;
        eo.x = (unsigned short)f2bf(acc_s[tt][0]);
        eo.y = (unsigned short)f2bf(acc_s[tt][1]);
        eo.z = (unsigned short)f2bf(acc_s[tt][2]);
        eo.w = (unsigned short)f2bf(acc_s[tt][3]);
        *(ushort4*)&sbf[ln][col] = eo;
        float4 ao = make_float4(acc_s[tt][0] * inv, acc_s[tt][1] * inv,
                                acc_s[tt][2] * inv, acc_s[tt][3] * inv);
        *(float4*)&arow[col] = ao;
    }

    // ---- phase 3: ctx = e @ V (wave reads only its own sbf chunk) ----
    f32x4 cacc0 = {0.f, 0.f, 0.f, 0.f}, cacc1 = {0.f, 0.f, 0.f, 0.f};
    const size_t vbase = ((size_t)(b * HH + h)) << 15;   // *32*1024
#pragma unroll
    for (int cch = 0; cch < 8; ++cch) {
        int k0 = kw + cch * 32;
        bf16x8 af = *(const bf16x8*)&sbf[ln][k0 + quad * 8];
        bf16x8 v0 = *(const bf16x8*)(vT + vbase + (((size_t)ln) << 10) + k0 + quad * 8);
        bf16x8 v1 = *(const bf16x8*)(vT + vbase + (((size_t)(16 + ln)) << 10) + k0 + quad * 8);
        cacc0 = __builtin_amdgcn_mfma_f32_16x16x32_bf16(af, v0, cacc0, 0, 0, 0);
        cacc1 = __builtin_amdgcn_mfma_f32_16x16x32_bf16(af, v1, cacc1, 0, 0, 0);
    }
    // cross-wave reduce slots carved from this wave's own sbf chunk
    // (rows 0,2,4,6 x cols [kw, kw+256)); safe: only wave w reads/wrote that
    // chunk and its own reads are complete (in-order LDS per wave).
    {
        int s0 = lane, s1 = 64 + lane;
        *(f32x4*)(&sbf[0][0] + ((s0 >> 5) * 2) * 1032 + w * 256 + (s0 & 31) * 8) = cacc0;
        *(f32x4*)(&sbf[0][0] + ((s1 >> 5) * 2) * 1032 + w * 256 + (s1 & 31) * 8) = cacc1;
    }
    __syncthreads();
    if (tid < 128) {
        int nt = tid >> 6, l2 = tid & 63;
        int s = nt * 64 + l2;
        int roff = ((s >> 5) * 2) * 1032 + (s & 31) * 8;
        f32x4 s4 = *(const f32x4*)(&sbf[0][0] + roff + 0 * 256) +
                   *(const f32x4*)(&sbf[0][0] + roff + 1 * 256) +
                   *(const f32x4*)(&sbf[0][0] + roff + 2 * 256) +
                   *(const f32x4*)(&sbf[0][0] + roff + 3 * 256);
        int qd = l2 >> 4, lc = l2 & 15;
#pragma unroll
        for (int r = 0; r < 4; ++r) {
            int qq = qd * 4 + r;
            ctx[((size_t)(b * SS + q0 + qq)) * DD + h * DH + nt * 16 + lc] =
                s4[r] * invLDS[qq];
        }
    }
}

// ---------------------------------------------------------------------------
// fp32 GEMM for the output projection (kept fp32 for accuracy headroom)
// ---------------------------------------------------------------------------
__global__ __launch_bounds__(256) void gemm_bias_kernel(
    const float* __restrict__ A, const float* __restrict__ W,
    const float* __restrict__ bias, float* __restrict__ C) {
    __shared__ float Asm[64][20];
    __shared__ float Wsm[16][72];
    const int tid = threadIdx.x;
    const int tx = tid & 15, ty = tid >> 4;
    const int m0 = blockIdx.x * 64, n0 = blockIdx.y * 64;
    const int lr = tid >> 2;
    const int lk4 = (tid & 3) * 4;
    const int wk = tid >> 4;
    const int wn4 = (tid & 15) * 4;
    float acc[4][4] = {};
    for (int k0 = 0; k0 < 512; k0 += 16) {
        __syncthreads();
        *(float4*)&Asm[lr][lk4] =
            *(const float4*)(A + (size_t)(m0 + lr) * 512 + k0 + lk4);
        *(float4*)&Wsm[wk][wn4] =
            *(const float4*)(W + (size_t)(k0 + wk) * 512 + n0 + wn4);
        __syncthreads();
#pragma unroll
        for (int kk4 = 0; kk4 < 16; kk4 += 4) {
            float4 w0 = *(const float4*)&Wsm[kk4 + 0][tx * 4];
            float4 w1 = *(const float4*)&Wsm[kk4 + 1][tx * 4];
            float4 w2 = *(const float4*)&Wsm[kk4 + 2][tx * 4];
            float4 w3 = *(const float4*)&Wsm[kk4 + 3][tx * 4];
#pragma unroll
            for (int i = 0; i < 4; ++i) {
                float4 a4 = *(const float4*)&Asm[ty * 4 + i][kk4];
                acc[i][0] += a4.x * w0.x + a4.y * w1.x + a4.z * w2.x + a4.w * w3.x;
                acc[i][1] += a4.x * w0.y + a4.y * w1.y + a4.z * w2.y + a4.w * w3.y;
                acc[i][2] += a4.x * w0.z + a4.y * w1.z + a4.z * w2.z + a4.w * w3.z;
                acc[i][3] += a4.x * w0.w + a4.y * w1.w + a4.z * w2.w + a4.w * w3.w;
            }
        }
    }
    float4 bv = *(const float4*)(bias + n0 + tx * 4);
#pragma unroll
    for (int i = 0; i < 4; ++i) {
        float4 o;
        o.x = acc[i][0] + bv.x; o.y = acc[i][1] + bv.y;
        o.z = acc[i][2] + bv.z; o.w = acc[i][3] + bv.w;
        *(float4*)(C + (size_t)(m0 + ty * 4 + i) * 512 + n0 + tx * 4) = o;
    }
}

// ---------------------------------------------------------------------------
extern "C" void kernel_launch(void* const* d_in, const int* in_sizes, int n_in,
                              void* d_out, int out_size, void* d_ws, size_t ws_size,
                              hipStream_t stream) {
    const float* query = (const float*)d_in[0];
    const float* key   = (const float*)d_in[1];
    const float* value = (const float*)d_in[2];
    const unsigned char* mask_raw = (const unsigned char*)d_in[3];
    const float* enc   = (const float*)d_in[4];
    const float* Wq    = (const float*)d_in[5];
    const float* bq    = (const float*)d_in[6];
    const float* Wk    = (const float*)d_in[7];
    const float* Wv    = (const float*)d_in[8];
    const float* Wp    = (const float*)d_in[9];
    const float* u_b   = (const float*)d_in[10];
    const float* v_b   = (const float*)d_in[11];
    const float* Wo    = (const float*)d_in[12];
    const float* bo    = (const float*)d_in[13];

    char* wsb = (char*)d_ws;
    float*          qprj = (float*)(wsb + 0);                     // 8 MB fp32
    unsigned short* kprj = (unsigned short*)(wsb + 8388608);      // 4 MB bf16
    unsigned short* vT   = (unsigned short*)(wsb + 12582912);     // 4 MB bf16
    unsigned short* pprj = (unsigned short*)(wsb + 16777216);     // 1 MB bf16
    int*            mnrm = (int*)(wsb + 17825792);                // 16 KB
    float*          ctx  = (float*)(wsb + 17842176);              // 8 MB fp32
    // transients alias the ctx region (dead before fused_attn writes ctx)
    unsigned short* qbf  = (unsigned short*)(wsb + 17842176);
    unsigned short* kbf  = (unsigned short*)(wsb + 22036480);
    unsigned short* vbf  = (unsigned short*)(wsb + 26230784);
    unsigned short* ebf  = (unsigned short*)(wsb + 30425088);
    unsigned short* WqT  = (unsigned short*)(wsb + 31473664);
    unsigned short* WkT  = (unsigned short*)(wsb + 31997952);
    unsigned short* WvT  = (unsigned short*)(wsb + 32522240);
    unsigned short* WpT  = (unsigned short*)(wsb + 33046528);

    float* outp = (float*)d_out;                 // (B,S,D)
    float* attn = outp + (size_t)BB * SS * DD;   // (B,H,S,S)

    mask_prep_kernel<<<1, 256, 0, stream>>>(mask_raw, mnrm);

    conv_kernel<<<2048, 256, 0, stream>>>(query, qbf, 524288);
    conv_kernel<<<2048, 256, 0, stream>>>(key, kbf, 524288);
    conv_kernel<<<2048, 256, 0, stream>>>(value, vbf, 524288);
    conv_kernel<<<512, 256, 0, stream>>>(enc, ebf, 131072);

    tconv_kernel<<<dim3(8, 8), 256, 0, stream>>>(Wq, WqT);
    tconv_kernel<<<dim3(8, 8), 256, 0, stream>>>(Wk, WkT);
    tconv_kernel<<<dim3(8, 8), 256, 0, stream>>>(Wv, WvT);
    tconv_kernel<<<dim3(8, 8), 256, 0, stream>>>(Wp, WpT);

    gemm_mfma_kernel<0><<<dim3(32, 4), 256, 0, stream>>>(qbf, WqT, bq, qprj, 512);
    gemm_mfma_kernel<1><<<dim3(32, 4), 256, 0, stream>>>(kbf, WkT, nullptr, kprj, 512);
    gemm_mfma_kernel<2><<<dim3(4, 32), 256, 0, stream>>>(WvT, vbf, nullptr, vT, 4096);
    gemm_mfma_kernel<1><<<dim3(8, 4), 256, 0, stream>>>(ebf, WpT, nullptr, pprj, 512);

    fused_attn_kernel<<<dim3(SS / 16, HH, BB), 256, 0, stream>>>(
        qprj, kprj, pprj, vT, u_b, v_b, mnrm, attn, ctx);

    gemm_bias_kernel<<<dim3(64, 8), 256, 0, stream>>>(ctx, Wo, bo, outp);
}

// Round 3
// 514.043 us; speedup vs baseline: 1.1319x; 1.1319x over previous
//
#include <hip/hip_runtime.h>

#define BB 4
#define SS 1024
#define DD 512
#define HH 16
#define DH 32

typedef __attribute__((ext_vector_type(8))) short bf16x8;
typedef __attribute__((ext_vector_type(4))) float f32x4;

__device__ __forceinline__ short f2bf(float x) {
    union { float f; unsigned u; } v; v.f = x;
    unsigned r = (v.u + 0x7FFFu + ((v.u >> 16) & 1u)) >> 16;
    return (short)r;
}
__device__ __forceinline__ float bf2f(unsigned short u) {
    union { unsigned u; float f; } v; v.u = ((unsigned)u) << 16;
    return v.f;
}
__device__ __forceinline__ void gl_lds16(const void* g, void* l) {
    __builtin_amdgcn_global_load_lds(
        (const __attribute__((address_space(1))) unsigned int*)g,
        (__attribute__((address_space(3))) unsigned int*)l, 16, 0, 0);
}

// ---------------------------------------------------------------------------
// Mask normalization: detect byte-bool vs int32 layout, expand to int[4096].
// ---------------------------------------------------------------------------
__global__ void mask_prep_kernel(const unsigned char* __restrict__ raw,
                                 int* __restrict__ norm) {
    __shared__ int bad;
    if (threadIdx.x == 0) bad = 0;
    __syncthreads();
    const unsigned int* w = (const unsigned int*)raw;
    int isbad = 0;
    for (int i = threadIdx.x; i < 1024; i += 256)
        if (w[i] > 1u) isbad = 1;
    if (isbad) atomicOr(&bad, 1);
    __syncthreads();
    if (bad) {
        for (int i = threadIdx.x; i < BB * SS; i += 256)
            norm[i] = raw[i] != 0;
    } else {
        const int* wi = (const int*)raw;
        for (int i = threadIdx.x; i < BB * SS; i += 256)
            norm[i] = wi[i] != 0;
    }
}

// ---------------------------------------------------------------------------
// Elementwise fp32 -> bf16 convert (n4 = number of float4 groups)
// ---------------------------------------------------------------------------
__global__ __launch_bounds__(256) void conv_kernel(
    const float* __restrict__ x, unsigned short* __restrict__ y, int n4) {
    int i = blockIdx.x * 256 + threadIdx.x;
    if (i < n4) {
        float4 v = ((const float4*)x)[i];
        ushort4 o;
        o.x = (unsigned short)f2bf(v.x); o.y = (unsigned short)f2bf(v.y);
        o.z = (unsigned short)f2bf(v.z); o.w = (unsigned short)f2bf(v.w);
        ((ushort4*)y)[i] = o;
    }
}

// ---------------------------------------------------------------------------
// 512x512 transpose + convert: WT[n][k] = bf16(W[k][n])
// ---------------------------------------------------------------------------
__global__ __launch_bounds__(256) void tconv_kernel(
    const float* __restrict__ W, unsigned short* __restrict__ WT) {
    __shared__ float t[64][68];
    const int bx = blockIdx.x * 64, by = blockIdx.y * 64;
    const int tid = threadIdx.x;
    const int r = tid >> 4, c4 = (tid & 15) * 4;
#pragma unroll
    for (int i = 0; i < 4; ++i) {
        float4 v = *(const float4*)(W + (size_t)(bx + r + i * 16) * 512 + by + c4);
        t[r + i * 16][c4 + 0] = v.x; t[r + i * 16][c4 + 1] = v.y;
        t[r + i * 16][c4 + 2] = v.z; t[r + i * 16][c4 + 3] = v.w;
    }
    __syncthreads();
#pragma unroll
    for (int i = 0; i < 4; ++i) {
        int c = r + i * 16;
        ushort4 o;
        o.x = (unsigned short)f2bf(t[c4 + 0][c]);
        o.y = (unsigned short)f2bf(t[c4 + 1][c]);
        o.z = (unsigned short)f2bf(t[c4 + 2][c]);
        o.w = (unsigned short)f2bf(t[c4 + 3][c]);
        *(ushort4*)(WT + (size_t)(by + c) * 512 + bx + c4) = o;
    }
}

// ---------------------------------------------------------------------------
// bf16 MFMA GEMM: C[M x N] = A[M x 512] @ BT[N x 512]^T
// 128x128 tile, BK=64, global_load_lds staging with XOR slot swizzle
// (conflict-free ds_read_b128 fragments). MODE 0: fp32 out + bias;
// MODE 1: bf16 out row-major; MODE 2: bf16 out in vT[b][h][dh][s] layout.
// ---------------------------------------------------------------------------
template <int MODE>
__global__ __launch_bounds__(256) void gemm_mfma_kernel(
    const unsigned short* __restrict__ A, const unsigned short* __restrict__ BT,
    const float* __restrict__ bias, void* __restrict__ Cout, int N) {
    __shared__ unsigned short As[128 * 64];
    __shared__ unsigned short Bs[128 * 64];
    const int tid = threadIdx.x;
    const int w = tid >> 6, lane = tid & 63;
    const int wm = w >> 1, wn = w & 1;
    const int ln = lane & 15, quad = lane >> 4;
    const int m0 = blockIdx.x * 128, n0 = blockIdx.y * 128;
    f32x4 acc[4][4] = {};
    for (int k0 = 0; k0 < 512; k0 += 64) {
        __syncthreads();
#pragma unroll
        for (int i = 0; i < 4; ++i) {
            int slot = i * 256 + tid;
            int row = slot >> 3, sl = slot & 7;
            int gsl = sl ^ (row & 7);
            gl_lds16(A + (size_t)(m0 + row) * 512 + k0 + gsl * 8, As + slot * 8);
            gl_lds16(BT + (size_t)(n0 + row) * 512 + k0 + gsl * 8, Bs + slot * 8);
        }
        __syncthreads();
#pragma unroll
        for (int kc = 0; kc < 2; ++kc) {
            bf16x8 af[4], bfr[4];
#pragma unroll
            for (int mt = 0; mt < 4; ++mt) {
                int row = wm * 64 + mt * 16 + ln;
                int sl = (kc * 4 + quad) ^ (row & 7);
                af[mt] = *(const bf16x8*)(As + row * 64 + sl * 8);
            }
#pragma unroll
            for (int nt = 0; nt < 4; ++nt) {
                int row = wn * 64 + nt * 16 + ln;
                int sl = (kc * 4 + quad) ^ (row & 7);
                bfr[nt] = *(const bf16x8*)(Bs + row * 64 + sl * 8);
            }
#pragma unroll
            for (int mt = 0; mt < 4; ++mt)
#pragma unroll
                for (int nt = 0; nt < 4; ++nt)
                    acc[mt][nt] = __builtin_amdgcn_mfma_f32_16x16x32_bf16(
                        af[mt], bfr[nt], acc[mt][nt], 0, 0, 0);
        }
    }
#pragma unroll
    for (int mt = 0; mt < 4; ++mt) {
#pragma unroll
        for (int nt = 0; nt < 4; ++nt) {
            int col = n0 + wn * 64 + nt * 16 + ln;
#pragma unroll
            for (int r = 0; r < 4; ++r) {
                int row = m0 + wm * 64 + mt * 16 + quad * 4 + r;
                float v = acc[mt][nt][r];
                if (MODE == 0) {
                    ((float*)Cout)[(size_t)row * N + col] = v + bias[col];
                } else if (MODE == 1) {
                    ((unsigned short*)Cout)[(size_t)row * N + col] =
                        (unsigned short)f2bf(v);
                } else {
                    int hh = row >> 5, dh = row & 31;
                    int bb = col >> 10, si = col & 1023;
                    ((unsigned short*)Cout)[(((size_t)(bb * HH + hh) * 32 + dh) << 10) + si] =
                        (unsigned short)f2bf(v);
                }
            }
        }
    }
}

// ---------------------------------------------------------------------------
// Fused attention (swapped-operand layout q=ln, k=quad*4+r per 16-tile):
//   phase 1: scores into registers; pos staged via per-wave LDS windows.
//   phase 2: softmax lane-local rows (2 shfl + tiny cross-wave bounce).
//   phase 2.5+3 (per 64-col sub-chunk): stage normalized fp32 attn in a
//     per-wave [16][68] LDS tile -> full-line 256B/row attn stores; read
//     MFMA A-frags back from the same tile (f2bf) -> ctx accumulate.
//   No big e-buffer: LDS 25.6 KB. ctx written as bf16 for the MFMA out-proj.
// ---------------------------------------------------------------------------
__global__ __launch_bounds__(256, 4) void fused_attn_kernel(
    const float* __restrict__ qp, const unsigned short* __restrict__ kp,
    const unsigned short* __restrict__ pp, const unsigned short* __restrict__ vT,
    const float* __restrict__ ub, const float* __restrict__ vb,
    const int* __restrict__ mask, float* __restrict__ attn,
    unsigned short* __restrict__ ctxbf) {
    const int b = blockIdx.z, h = blockIdx.y, q0 = blockIdx.x * 16;
    const int tid = threadIdx.x;
    const int w = tid >> 6, lane = tid & 63;
    const int ln = lane & 15, quad = lane >> 4;

    // 25600 B shared pool:
    //   phase 1: posb slices, per wave w*5632B (2 windows x 16 x 88 ushort)
    //   phase 2.5/3: stage slices, per wave w*4352B ([16][68] fp32)  [0..17408)
    //               red reduce buffer [17408..25600)
    // posb is dead before any stage/red write (separated by softmax barriers).
    __shared__ __align__(16) unsigned char smem[25600];
    __shared__ float rowred[2][4][16];

    unsigned short* posb = (unsigned short*)smem + w * 2816;

    // ---- phase 1: S^T score tiles into registers ----
    bf16x8 a_c, a_pA, a_pB;
    {
        const float* qrow = qp + ((size_t)(b * SS + q0 + ln)) * DD + h * DH + quad * 8;
        const int qrB = q0 + ln + 1;
        const float* qrowB = qp + ((size_t)(b * SS + qrB)) * DD + h * DH + quad * 8;
#pragma unroll
        for (int j = 0; j < 8; ++j) {
            float uu = ub[h * DH + quad * 8 + j];
            float vv = vb[h * DH + quad * 8 + j];
            float qv = qrow[j];
            a_c[j] = f2bf(qv + uu);
            a_pA[j] = f2bf(qv + vv);
            a_pB[j] = (qrB < SS) ? f2bf(qrowB[j] + vv) : (short)0;
        }
    }
    const unsigned short* pbase = pp + h * DH + quad * 8;
    const int kw = w * 256;
    f32x4 acc_s[16];
#pragma unroll
    for (int c = 0; c < 4; ++c) {
        const int k0 = kw + c * 64;
        const bool needA = (k0 <= q0 + 15);
        const bool needB = (k0 + 63 >= q0 + 1);
        if (needA) {
            const int jA0 = k0 - q0 + SS - 16;
#pragma unroll
            for (int t = 0; t < 5; ++t) {
                int j = jA0 + t * 16 + ln;
                bf16x8 bp;
                if ((unsigned)j < (unsigned)SS) {
                    bp = *(const bf16x8*)(pbase + (size_t)j * DD);
                } else {
#pragma unroll
                    for (int jj = 0; jj < 8; ++jj) bp[jj] = (short)0;
                }
                f32x4 acc = {0.f, 0.f, 0.f, 0.f};
                acc = __builtin_amdgcn_mfma_f32_16x16x32_bf16(bp, a_pA, acc, 0, 0, 0);
                ushort4 o;
                o.x = (unsigned short)f2bf(acc[0]);
                o.y = (unsigned short)f2bf(acc[1]);
                o.z = (unsigned short)f2bf(acc[2]);
                o.w = (unsigned short)f2bf(acc[3]);
                *(ushort4*)(posb + ln * 88 + t * 16 + quad * 4) = o;
            }
        }
        if (needB) {
            const int jB0 = k0 - q0 - 17;
#pragma unroll
            for (int t = 0; t < 5; ++t) {
                int j = jB0 + t * 16 + ln;
                bf16x8 bp;
                if ((unsigned)j < (unsigned)SS) {
                    bp = *(const bf16x8*)(pbase + (size_t)j * DD);
                } else {
#pragma unroll
                    for (int jj = 0; jj < 8; ++jj) bp[jj] = (short)0;
                }
                f32x4 acc = {0.f, 0.f, 0.f, 0.f};
                acc = __builtin_amdgcn_mfma_f32_16x16x32_bf16(bp, a_pB, acc, 0, 0, 0);
                ushort4 o;
                o.x = (unsigned short)f2bf(acc[0]);
                o.y = (unsigned short)f2bf(acc[1]);
                o.z = (unsigned short)f2bf(acc[2]);
                o.w = (unsigned short)f2bf(acc[3]);
                *(ushort4*)(posb + 1408 + ln * 88 + t * 16 + quad * 4) = o;
            }
        }
        asm volatile("s_waitcnt lgkmcnt(0)" ::: "memory");
#pragma unroll
        for (int t = 0; t < 4; ++t) {
            const int kk0 = k0 + t * 16;
            bf16x8 bk = *(const bf16x8*)(
                kp + ((size_t)(b * SS + kk0 + ln)) * DD + h * DH + quad * 8);
            f32x4 acc = {0.f, 0.f, 0.f, 0.f};
            acc = __builtin_amdgcn_mfma_f32_16x16x32_bf16(bk, a_c, acc, 0, 0, 0);
#pragma unroll
            for (int r = 0; r < 4; ++r) {
                const int kkl = t * 16 + quad * 4 + r;
                const int which = (k0 + kkl <= q0 + ln) ? 0 : 1;
                acc[r] += bf2f(posb[which * 1408 + ln * 88 + (kkl - ln + 15)]);
            }
            acc_s[c * 4 + t] = acc;
        }
    }

    // ---- phase 2: softmax (row = ln, lane-local) ----
    const float scale = 0.04419417382415922f;   // 1/sqrt(512)
    const int* mrow = mask + ((size_t)b << 10);
    float mx = -3.4e38f;
#pragma unroll
    for (int tt = 0; tt < 16; ++tt) {
        int col = kw + tt * 16 + quad * 4;
        int4 mm = *(const int4*)(mrow + col);
        float v0 = mm.x ? -1e9f : acc_s[tt][0] * scale;
        float v1 = mm.y ? -1e9f : acc_s[tt][1] * scale;
        float v2 = mm.z ? -1e9f : acc_s[tt][2] * scale;
        float v3 = mm.w ? -1e9f : acc_s[tt][3] * scale;
        acc_s[tt][0] = v0; acc_s[tt][1] = v1;
        acc_s[tt][2] = v2; acc_s[tt][3] = v3;
        mx = fmaxf(mx, fmaxf(fmaxf(v0, v1), fmaxf(v2, v3)));
    }
    mx = fmaxf(mx, __shfl_xor(mx, 16, 64));
    mx = fmaxf(mx, __shfl_xor(mx, 32, 64));
    if (quad == 0) rowred[0][w][ln] = mx;
    __syncthreads();   // all waves past phase 1 (posb dead from here)
    float gm = fmaxf(fmaxf(rowred[0][0][ln], rowred[0][1][ln]),
                     fmaxf(rowred[0][2][ln], rowred[0][3][ln]));
    float sm = 0.f;
#pragma unroll
    for (int tt = 0; tt < 16; ++tt) {
#pragma unroll
        for (int r = 0; r < 4; ++r) {
            float e = __expf(acc_s[tt][r] - gm);
            acc_s[tt][r] = e;
            sm += e;
        }
    }
    sm += __shfl_xor(sm, 16, 64);
    sm += __shfl_xor(sm, 32, 64);
    if (quad == 0) rowred[1][w][ln] = sm;
    __syncthreads();
    float l = rowred[1][0][ln] + rowred[1][1][ln] +
              rowred[1][2][ln] + rowred[1][3][ln];
    float inv = 1.f / l;

    // ---- phase 2.5 + 3: per 64-col sub-chunk, stage fp32 attn in LDS,
    //      wide attn stores, then MFMA A-frags from the same tile ----
    float* stg = (float*)(smem + (size_t)w * 4352);   // [16][68] fp32
    f32x4 cacc0 = {0.f, 0.f, 0.f, 0.f}, cacc1 = {0.f, 0.f, 0.f, 0.f};
    const size_t vbase = ((size_t)(b * HH + h)) << 15;   // *32*1024
    float* abase = attn + (((size_t)(b * HH + h)) << 20) + (size_t)q0 * SS;
#pragma unroll
    for (int s = 0; s < 4; ++s) {
        // stage normalized attn (wave-private tile; wave-order LDS ops)
#pragma unroll
        for (int t = 0; t < 4; ++t) {
            int tt = s * 4 + t;
            float4 o = make_float4(acc_s[tt][0] * inv, acc_s[tt][1] * inv,
                                   acc_s[tt][2] * inv, acc_s[tt][3] * inv);
            *(float4*)&stg[ln * 68 + t * 16 + quad * 4] = o;
        }
        // full-line attn stores: 4 rows x 256B contiguous per instruction
#pragma unroll
        for (int i = 0; i < 4; ++i) {
            int row = i * 4 + quad;
            int c4 = ln * 4;
            float4 v = *(float4*)&stg[row * 68 + c4];
            *(float4*)&abase[(size_t)row * SS + kw + s * 64 + c4] = v;
        }
        // phase-3 MFMA for the two 32-col tiles of this sub-chunk
#pragma unroll
        for (int cc = 0; cc < 2; ++cc) {
            int coff = cc * 32 + quad * 8;
            float4 pa = *(float4*)&stg[ln * 68 + coff];
            float4 pb = *(float4*)&stg[ln * 68 + coff + 4];
            bf16x8 af;
            af[0] = f2bf(pa.x); af[1] = f2bf(pa.y);
            af[2] = f2bf(pa.z); af[3] = f2bf(pa.w);
            af[4] = f2bf(pb.x); af[5] = f2bf(pb.y);
            af[6] = f2bf(pb.z); af[7] = f2bf(pb.w);
            int k0 = kw + s * 64 + cc * 32;
            bf16x8 v0 = *(const bf16x8*)(vT + vbase + (((size_t)ln) << 10) + k0 + quad * 8);
            bf16x8 v1 = *(const bf16x8*)(vT + vbase + (((size_t)(16 + ln)) << 10) + k0 + quad * 8);
            cacc0 = __builtin_amdgcn_mfma_f32_16x16x32_bf16(af, v0, cacc0, 0, 0, 0);
            cacc1 = __builtin_amdgcn_mfma_f32_16x16x32_bf16(af, v1, cacc1, 0, 0, 0);
        }
    }

    // cross-wave ctx reduce through dedicated red region (disjoint from stg)
    f32x4* red = (f32x4*)(smem + 17408);
    red[(w * 2 + 0) * 64 + lane] = cacc0;
    red[(w * 2 + 1) * 64 + lane] = cacc1;
    __syncthreads();
    if (tid < 128) {
        int nt = tid >> 6, l2 = tid & 63;
        f32x4 s4 = red[(0 * 2 + nt) * 64 + l2] + red[(1 * 2 + nt) * 64 + l2] +
                   red[(2 * 2 + nt) * 64 + l2] + red[(3 * 2 + nt) * 64 + l2];
        int qd = l2 >> 4, lc = l2 & 15;
#pragma unroll
        for (int r = 0; r < 4; ++r) {
            int qq = qd * 4 + r;
            ctxbf[((size_t)(b * SS + q0 + qq)) * DD + h * DH + nt * 16 + lc] =
                (unsigned short)f2bf(s4[r]);
        }
    }
}

// ---------------------------------------------------------------------------
extern "C" void kernel_launch(void* const* d_in, const int* in_sizes, int n_in,
                              void* d_out, int out_size, void* d_ws, size_t ws_size,
                              hipStream_t stream) {
    const float* query = (const float*)d_in[0];
    const float* key   = (const float*)d_in[1];
    const float* value = (const float*)d_in[2];
    const unsigned char* mask_raw = (const unsigned char*)d_in[3];
    const float* enc   = (const float*)d_in[4];
    const float* Wq    = (const float*)d_in[5];
    const float* bq    = (const float*)d_in[6];
    const float* Wk    = (const float*)d_in[7];
    const float* Wv    = (const float*)d_in[8];
    const float* Wp    = (const float*)d_in[9];
    const float* u_b   = (const float*)d_in[10];
    const float* v_b   = (const float*)d_in[11];
    const float* Wo    = (const float*)d_in[12];
    const float* bo    = (const float*)d_in[13];

    char* wsb = (char*)d_ws;
    float*          qprj = (float*)(wsb + 0);                     // 8 MB fp32
    unsigned short* kprj = (unsigned short*)(wsb + 8388608);      // 4 MB bf16
    unsigned short* vT   = (unsigned short*)(wsb + 12582912);     // 4 MB bf16
    unsigned short* pprj = (unsigned short*)(wsb + 16777216);     // 1 MB bf16
    int*            mnrm = (int*)(wsb + 17825792);                // 16 KB
    unsigned short* ctxbf= (unsigned short*)(wsb + 17842176);     // 4 MB bf16
    // WoT over the dead kbf region (kbf consumed before Wo tconv runs)
    unsigned short* WoT  = (unsigned short*)(wsb + 22036480);     // 512 KB
    // transients (dead before fused_attn writes ctxbf / WoT tconv)
    unsigned short* qbf  = (unsigned short*)(wsb + 17842176);
    unsigned short* kbf  = (unsigned short*)(wsb + 22036480);
    unsigned short* vbf  = (unsigned short*)(wsb + 26230784);
    unsigned short* ebf  = (unsigned short*)(wsb + 30425088);
    unsigned short* WqT  = (unsigned short*)(wsb + 31473664);
    unsigned short* WkT  = (unsigned short*)(wsb + 31997952);
    unsigned short* WvT  = (unsigned short*)(wsb + 32522240);
    unsigned short* WpT  = (unsigned short*)(wsb + 33046528);

    float* outp = (float*)d_out;                 // (B,S,D)
    float* attn = outp + (size_t)BB * SS * DD;   // (B,H,S,S)

    mask_prep_kernel<<<1, 256, 0, stream>>>(mask_raw, mnrm);

    conv_kernel<<<2048, 256, 0, stream>>>(query, qbf, 524288);
    conv_kernel<<<2048, 256, 0, stream>>>(key, kbf, 524288);
    conv_kernel<<<2048, 256, 0, stream>>>(value, vbf, 524288);
    conv_kernel<<<512, 256, 0, stream>>>(enc, ebf, 131072);

    tconv_kernel<<<dim3(8, 8), 256, 0, stream>>>(Wq, WqT);
    tconv_kernel<<<dim3(8, 8), 256, 0, stream>>>(Wk, WkT);
    tconv_kernel<<<dim3(8, 8), 256, 0, stream>>>(Wv, WvT);
    tconv_kernel<<<dim3(8, 8), 256, 0, stream>>>(Wp, WpT);

    // NOTE: qbf aliases ctxbf but is consumed by this gemm before fused_attn
    gemm_mfma_kernel<0><<<dim3(32, 4), 256, 0, stream>>>(qbf, WqT, bq, qprj, 512);
    gemm_mfma_kernel<1><<<dim3(32, 4), 256, 0, stream>>>(kbf, WkT, nullptr, kprj, 512);
    gemm_mfma_kernel<2><<<dim3(4, 32), 256, 0, stream>>>(WvT, vbf, nullptr, vT, 4096);
    gemm_mfma_kernel<1><<<dim3(8, 4), 256, 0, stream>>>(ebf, WpT, nullptr, pprj, 512);

    // Wo transpose after kbf is dead (WoT reuses its region)
    tconv_kernel<<<dim3(8, 8), 256, 0, stream>>>(Wo, WoT);

    fused_attn_kernel<<<dim3(SS / 16, HH, BB), 256, 0, stream>>>(
        qprj, kprj, pprj, vT, u_b, v_b, mnrm, attn, ctxbf);

    // output projection on matrix cores (replaces fp32 gemm_bias)
    gemm_mfma_kernel<0><<<dim3(32, 4), 256, 0, stream>>>(ctxbf, WoT, bo, outp, 512);
}

// Round 6
// 479.526 us; speedup vs baseline: 1.2134x; 1.0720x over previous
//
#include <hip/hip_runtime.h>

#define BB 4
#define SS 1024
#define DD 512
#define HH 16
#define DH 32

typedef __attribute__((ext_vector_type(8))) short bf16x8;
typedef __attribute__((ext_vector_type(4))) float f32x4;

__device__ __forceinline__ short f2bf(float x) {
    union { float f; unsigned u; } v; v.f = x;
    unsigned r = (v.u + 0x7FFFu + ((v.u >> 16) & 1u)) >> 16;
    return (short)r;
}
__device__ __forceinline__ float bf2f(unsigned short u) {
    union { unsigned u; float f; } v; v.u = ((unsigned)u) << 16;
    return v.f;
}
__device__ __forceinline__ void gl_lds16(const void* g, void* l) {
    __builtin_amdgcn_global_load_lds(
        (const __attribute__((address_space(1))) unsigned int*)g,
        (__attribute__((address_space(3))) unsigned int*)l, 16, 0, 0);
}

// ---------------------------------------------------------------------------
// Merged preprocessing: fp32->bf16 converts (q,k,v,enc), 4 weight transposes,
// mask normalization. One launch instead of nine.
//   blocks [0,2048): query conv     [2048,4096): key conv
//   blocks [4096,6144): value conv  [6144,6656): enc conv
//   blocks [6656,6912): tconv Wq/Wk/Wv/Wp (64 blocks each)
//   block 6912: mask normalization
// ---------------------------------------------------------------------------
__global__ __launch_bounds__(256) void prep_kernel(
    const float* __restrict__ query, const float* __restrict__ key,
    const float* __restrict__ value, const float* __restrict__ enc,
    const float* __restrict__ Wq, const float* __restrict__ Wk,
    const float* __restrict__ Wv, const float* __restrict__ Wp,
    const unsigned char* __restrict__ mask_raw,
    unsigned short* __restrict__ qbf, unsigned short* __restrict__ kbf,
    unsigned short* __restrict__ vbf, unsigned short* __restrict__ ebf,
    unsigned short* __restrict__ WqT, unsigned short* __restrict__ WkT,
    unsigned short* __restrict__ WvT, unsigned short* __restrict__ WpT,
    int* __restrict__ mnrm) {
    __shared__ float t[64][68];
    __shared__ int bad;
    const int bid = blockIdx.x;
    const int tid = threadIdx.x;
    if (bid < 6656) {
        const float* x; unsigned short* y; int base;
        if (bid < 2048)      { x = query; y = qbf; base = bid; }
        else if (bid < 4096) { x = key;   y = kbf; base = bid - 2048; }
        else if (bid < 6144) { x = value; y = vbf; base = bid - 4096; }
        else                 { x = enc;   y = ebf; base = bid - 6144; }
        int i = base * 256 + tid;
        float4 v = ((const float4*)x)[i];
        ushort4 o;
        o.x = (unsigned short)f2bf(v.x); o.y = (unsigned short)f2bf(v.y);
        o.z = (unsigned short)f2bf(v.z); o.w = (unsigned short)f2bf(v.w);
        ((ushort4*)y)[i] = o;
    } else if (bid < 6912) {
        int s = bid - 6656;
        int wsel = s >> 6;
        const float* W; unsigned short* WT;
        if (wsel == 0)      { W = Wq; WT = WqT; }
        else if (wsel == 1) { W = Wk; WT = WkT; }
        else if (wsel == 2) { W = Wv; WT = WvT; }
        else                { W = Wp; WT = WpT; }
        int idx = s & 63;
        const int bx = (idx >> 3) * 64, by = (idx & 7) * 64;
        const int r = tid >> 4, c4 = (tid & 15) * 4;
#pragma unroll
        for (int i = 0; i < 4; ++i) {
            float4 v = *(const float4*)(W + (size_t)(bx + r + i * 16) * 512 + by + c4);
            t[r + i * 16][c4 + 0] = v.x; t[r + i * 16][c4 + 1] = v.y;
            t[r + i * 16][c4 + 2] = v.z; t[r + i * 16][c4 + 3] = v.w;
        }
        __syncthreads();
#pragma unroll
        for (int i = 0; i < 4; ++i) {
            int c = r + i * 16;
            ushort4 o;
            o.x = (unsigned short)f2bf(t[c4 + 0][c]);
            o.y = (unsigned short)f2bf(t[c4 + 1][c]);
            o.z = (unsigned short)f2bf(t[c4 + 2][c]);
            o.w = (unsigned short)f2bf(t[c4 + 3][c]);
            *(ushort4*)(WT + (size_t)(by + c) * 512 + bx + c4) = o;
        }
    } else {
        if (tid == 0) bad = 0;
        __syncthreads();
        const unsigned int* w = (const unsigned int*)mask_raw;
        int isbad = 0;
        for (int i = tid; i < 1024; i += 256)
            if (w[i] > 1u) isbad = 1;
        if (isbad) atomicOr(&bad, 1);
        __syncthreads();
        if (bad) {
            for (int i = tid; i < BB * SS; i += 256)
                mnrm[i] = mask_raw[i] != 0;
        } else {
            const int* wi = (const int*)mask_raw;
            for (int i = tid; i < BB * SS; i += 256)
                mnrm[i] = wi[i] != 0;
        }
    }
}

// ---------------------------------------------------------------------------
// 512x512 transpose + convert (kept for Wo: its target aliases kbf, which is
// still live during the merged QKVP GEMM, so this must run after it)
// ---------------------------------------------------------------------------
__global__ __launch_bounds__(256) void tconv_kernel(
    const float* __restrict__ W, unsigned short* __restrict__ WT) {
    __shared__ float t[64][68];
    const int bx = blockIdx.x * 64, by = blockIdx.y * 64;
    const int tid = threadIdx.x;
    const int r = tid >> 4, c4 = (tid & 15) * 4;
#pragma unroll
    for (int i = 0; i < 4; ++i) {
        float4 v = *(const float4*)(W + (size_t)(bx + r + i * 16) * 512 + by + c4);
        t[r + i * 16][c4 + 0] = v.x; t[r + i * 16][c4 + 1] = v.y;
        t[r + i * 16][c4 + 2] = v.z; t[r + i * 16][c4 + 3] = v.w;
    }
    __syncthreads();
#pragma unroll
    for (int i = 0; i < 4; ++i) {
        int c = r + i * 16;
        ushort4 o;
        o.x = (unsigned short)f2bf(t[c4 + 0][c]);
        o.y = (unsigned short)f2bf(t[c4 + 1][c]);
        o.z = (unsigned short)f2bf(t[c4 + 2][c]);
        o.w = (unsigned short)f2bf(t[c4 + 3][c]);
        *(ushort4*)(WT + (size_t)(by + c) * 512 + bx + c4) = o;
    }
}

// ---------------------------------------------------------------------------
// bf16 MFMA GEMM body: C[M x N] = A[M x 512] @ BT[N x 512]^T, 128x128 tile,
// BK=64, global_load_lds + XOR swizzle. mode 0: fp32 + bias; mode 1: bf16
// row-major; mode 2: bf16 into vT[b][h][dh][s].
// ---------------------------------------------------------------------------
__device__ __forceinline__ void gemm_body(
    const unsigned short* __restrict__ A, const unsigned short* __restrict__ BT,
    const float* __restrict__ bias, void* __restrict__ Cout, int N, int mode,
    int m0, int n0, unsigned short* As, unsigned short* Bs) {
    const int tid = threadIdx.x;
    const int w = tid >> 6, lane = tid & 63;
    const int wm = w >> 1, wn = w & 1;
    const int ln = lane & 15, quad = lane >> 4;
    f32x4 acc[4][4] = {};
    for (int k0 = 0; k0 < 512; k0 += 64) {
        __syncthreads();
#pragma unroll
        for (int i = 0; i < 4; ++i) {
            int slot = i * 256 + tid;
            int row = slot >> 3, sl = slot & 7;
            int gsl = sl ^ (row & 7);
            gl_lds16(A + (size_t)(m0 + row) * 512 + k0 + gsl * 8, As + slot * 8);
            gl_lds16(BT + (size_t)(n0 + row) * 512 + k0 + gsl * 8, Bs + slot * 8);
        }
        __syncthreads();
#pragma unroll
        for (int kc = 0; kc < 2; ++kc) {
            bf16x8 af[4], bfr[4];
#pragma unroll
            for (int mt = 0; mt < 4; ++mt) {
                int row = wm * 64 + mt * 16 + ln;
                int sl = (kc * 4 + quad) ^ (row & 7);
                af[mt] = *(const bf16x8*)(As + row * 64 + sl * 8);
            }
#pragma unroll
            for (int nt = 0; nt < 4; ++nt) {
                int row = wn * 64 + nt * 16 + ln;
                int sl = (kc * 4 + quad) ^ (row & 7);
                bfr[nt] = *(const bf16x8*)(Bs + row * 64 + sl * 8);
            }
#pragma unroll
            for (int mt = 0; mt < 4; ++mt)
#pragma unroll
                for (int nt = 0; nt < 4; ++nt)
                    acc[mt][nt] = __builtin_amdgcn_mfma_f32_16x16x32_bf16(
                        af[mt], bfr[nt], acc[mt][nt], 0, 0, 0);
        }
    }
#pragma unroll
    for (int mt = 0; mt < 4; ++mt) {
#pragma unroll
        for (int nt = 0; nt < 4; ++nt) {
            int col = n0 + wn * 64 + nt * 16 + ln;
#pragma unroll
            for (int r = 0; r < 4; ++r) {
                int row = m0 + wm * 64 + mt * 16 + quad * 4 + r;
                float v = acc[mt][nt][r];
                if (mode == 0) {
                    ((float*)Cout)[(size_t)row * N + col] = v + bias[col];
                } else if (mode == 1) {
                    ((unsigned short*)Cout)[(size_t)row * N + col] =
                        (unsigned short)f2bf(v);
                } else {
                    int hh = row >> 5, dh = row & 31;
                    int bb = col >> 10, si = col & 1023;
                    ((unsigned short*)Cout)[(((size_t)(bb * HH + hh) * 32 + dh) << 10) + si] =
                        (unsigned short)f2bf(v);
                }
            }
        }
    }
}

// Merged Q/K/V/P projection GEMMs (one launch, 416 blocks):
//   [0,128): Q (mode0)  [128,256): K (mode1)  [256,384): V (mode2)  [384,416): P
__global__ __launch_bounds__(256) void gemm4_kernel(
    const unsigned short* __restrict__ qbf, const unsigned short* __restrict__ WqT,
    const float* __restrict__ bq, float* __restrict__ qprj,
    const unsigned short* __restrict__ kbf, const unsigned short* __restrict__ WkT,
    unsigned short* __restrict__ kprj,
    const unsigned short* __restrict__ vbf, const unsigned short* __restrict__ WvT,
    unsigned short* __restrict__ vT,
    const unsigned short* __restrict__ ebf, const unsigned short* __restrict__ WpT,
    unsigned short* __restrict__ pprj) {
    __shared__ unsigned short As[128 * 64];
    __shared__ unsigned short Bs[128 * 64];
    const int bid = blockIdx.x;
    const unsigned short *A, *BT; const float* bias = nullptr; void* C;
    int N = 512, mode, m0, n0;
    if (bid < 128) {
        A = qbf; BT = WqT; bias = bq; C = qprj; mode = 0;
        m0 = (bid >> 2) * 128; n0 = (bid & 3) * 128;
    } else if (bid < 256) {
        int s = bid - 128;
        A = kbf; BT = WkT; C = kprj; mode = 1;
        m0 = (s >> 2) * 128; n0 = (s & 3) * 128;
    } else if (bid < 384) {
        int s = bid - 256;
        A = WvT; BT = vbf; C = vT; mode = 2; N = 4096;
        m0 = (s >> 5) * 128; n0 = (s & 31) * 128;
    } else {
        int s = bid - 384;
        A = ebf; BT = WpT; C = pprj; mode = 1;
        m0 = (s >> 2) * 128; n0 = (s & 3) * 128;
    }
    gemm_body(A, BT, bias, C, N, mode, m0, n0, As, Bs);
}

// Output projection: ctx(bf16) @ WoT + bo -> fp32 out
__global__ __launch_bounds__(256) void gemm_out_kernel(
    const unsigned short* __restrict__ ctxbf, const unsigned short* __restrict__ WoT,
    const float* __restrict__ bo, float* __restrict__ outp) {
    __shared__ unsigned short As[128 * 64];
    __shared__ unsigned short Bs[128 * 64];
    const int bid = blockIdx.x;
    gemm_body(ctxbf, WoT, bo, outp, 512, 0, (bid >> 2) * 128, (bid & 3) * 128, As, Bs);
}

// ---------------------------------------------------------------------------
// Fused attention (swapped-operand layout q=ln, k=quad*4+r per 16-tile):
//   XCD-aware block swizzle: each XCD owns 8 whole (b,h) -> K/V/p L2-local.
//   K fragments preloaded per chunk; NO manual lgkmcnt drain (same-wave DS
//   ordering guarantees posb write->read; compiler inserts precise waits).
//   attn stores: full-line f32x4 rows, nontemporal (never re-read).
// ---------------------------------------------------------------------------
__global__ __launch_bounds__(256, 4) void fused_attn_kernel(
    const float* __restrict__ qp, const unsigned short* __restrict__ kp,
    const unsigned short* __restrict__ pp, const unsigned short* __restrict__ vT,
    const float* __restrict__ ub, const float* __restrict__ vb,
    const int* __restrict__ mask, float* __restrict__ attn,
    unsigned short* __restrict__ ctxbf) {
    // bijective XCD swizzle (4096 % 8 == 0): XCD x gets work [x*512,(x+1)*512)
    const int n = blockIdx.x + 64 * blockIdx.y + 1024 * blockIdx.z;
    const int swz = (n & 7) * 512 + (n >> 3);
    const int q0 = (swz & 63) * 16;
    const int h = (swz >> 6) & 15;
    const int b = swz >> 10;
    const int tid = threadIdx.x;
    const int w = tid >> 6, lane = tid & 63;
    const int ln = lane & 15, quad = lane >> 4;

    __shared__ __align__(16) unsigned char smem[25600];
    __shared__ float rowred[2][4][16];

    unsigned short* posb = (unsigned short*)smem + w * 2816;

    // ---- phase 1: S^T score tiles into registers ----
    bf16x8 a_c, a_pA, a_pB;
    {
        const float* qrow = qp + ((size_t)(b * SS + q0 + ln)) * DD + h * DH + quad * 8;
        const int qrB = q0 + ln + 1;
        const float* qrowB = qp + ((size_t)(b * SS + qrB)) * DD + h * DH + quad * 8;
#pragma unroll
        for (int j = 0; j < 8; ++j) {
            float uu = ub[h * DH + quad * 8 + j];
            float vv = vb[h * DH + quad * 8 + j];
            float qv = qrow[j];
            a_c[j] = f2bf(qv + uu);
            a_pA[j] = f2bf(qv + vv);
            a_pB[j] = (qrB < SS) ? f2bf(qrowB[j] + vv) : (short)0;
        }
    }
    const unsigned short* pbase = pp + h * DH + quad * 8;
    const int kw = w * 256;
    f32x4 acc_s[16];
#pragma unroll
    for (int c = 0; c < 4; ++c) {
        const int k0 = kw + c * 64;
        // K fragments preloaded first: independent of the pos path, so their
        // latency overlaps the pos MFMA + LDS staging below.
        bf16x8 bk[4];
#pragma unroll
        for (int t = 0; t < 4; ++t)
            bk[t] = *(const bf16x8*)(
                kp + ((size_t)(b * SS + k0 + t * 16 + ln)) * DD + h * DH + quad * 8);
        const bool needA = (k0 <= q0 + 15);
        const bool needB = (k0 + 63 >= q0 + 1);
        if (needA) {
            const int jA0 = k0 - q0 + SS - 16;
#pragma unroll
            for (int t = 0; t < 5; ++t) {
                int j = jA0 + t * 16 + ln;
                bf16x8 bp;
                if ((unsigned)j < (unsigned)SS) {
                    bp = *(const bf16x8*)(pbase + (size_t)j * DD);
                } else {
#pragma unroll
                    for (int jj = 0; jj < 8; ++jj) bp[jj] = (short)0;
                }
                f32x4 acc = {0.f, 0.f, 0.f, 0.f};
                acc = __builtin_amdgcn_mfma_f32_16x16x32_bf16(bp, a_pA, acc, 0, 0, 0);
                ushort4 o;
                o.x = (unsigned short)f2bf(acc[0]);
                o.y = (unsigned short)f2bf(acc[1]);
                o.z = (unsigned short)f2bf(acc[2]);
                o.w = (unsigned short)f2bf(acc[3]);
                *(ushort4*)(posb + ln * 88 + t * 16 + quad * 4) = o;
            }
        }
        if (needB) {
            const int jB0 = k0 - q0 - 17;
#pragma unroll
            for (int t = 0; t < 5; ++t) {
                int j = jB0 + t * 16 + ln;
                bf16x8 bp;
                if ((unsigned)j < (unsigned)SS) {
                    bp = *(const bf16x8*)(pbase + (size_t)j * DD);
                } else {
#pragma unroll
                    for (int jj = 0; jj < 8; ++jj) bp[jj] = (short)0;
                }
                f32x4 acc = {0.f, 0.f, 0.f, 0.f};
                acc = __builtin_amdgcn_mfma_f32_16x16x32_bf16(bp, a_pB, acc, 0, 0, 0);
                ushort4 o;
                o.x = (unsigned short)f2bf(acc[0]);
                o.y = (unsigned short)f2bf(acc[1]);
                o.z = (unsigned short)f2bf(acc[2]);
                o.w = (unsigned short)f2bf(acc[3]);
                *(ushort4*)(posb + 1408 + ln * 88 + t * 16 + quad * 4) = o;
            }
        }
        // no lgkmcnt drain: same-wave DS ops execute in order; the compiler
        // inserts precise waits before the posb-read consumers below.
#pragma unroll
        for (int t = 0; t < 4; ++t) {
            f32x4 acc = {0.f, 0.f, 0.f, 0.f};
            acc = __builtin_amdgcn_mfma_f32_16x16x32_bf16(bk[t], a_c, acc, 0, 0, 0);
#pragma unroll
            for (int r = 0; r < 4; ++r) {
                const int kkl = t * 16 + quad * 4 + r;
                const int which = (k0 + kkl <= q0 + ln) ? 0 : 1;
                acc[r] += bf2f(posb[which * 1408 + ln * 88 + (kkl - ln + 15)]);
            }
            acc_s[c * 4 + t] = acc;
        }
    }

    // ---- phase 2: softmax (row = ln, lane-local) ----
    const float scale = 0.04419417382415922f;   // 1/sqrt(512)
    const int* mrow = mask + ((size_t)b << 10);
    float mx = -3.4e38f;
#pragma unroll
    for (int tt = 0; tt < 16; ++tt) {
        int col = kw + tt * 16 + quad * 4;
        int4 mm = *(const int4*)(mrow + col);
        float v0 = mm.x ? -1e9f : acc_s[tt][0] * scale;
        float v1 = mm.y ? -1e9f : acc_s[tt][1] * scale;
        float v2 = mm.z ? -1e9f : acc_s[tt][2] * scale;
        float v3 = mm.w ? -1e9f : acc_s[tt][3] * scale;
        acc_s[tt][0] = v0; acc_s[tt][1] = v1;
        acc_s[tt][2] = v2; acc_s[tt][3] = v3;
        mx = fmaxf(mx, fmaxf(fmaxf(v0, v1), fmaxf(v2, v3)));
    }
    mx = fmaxf(mx, __shfl_xor(mx, 16, 64));
    mx = fmaxf(mx, __shfl_xor(mx, 32, 64));
    if (quad == 0) rowred[0][w][ln] = mx;
    __syncthreads();   // all waves past phase 1 (posb dead from here)
    float gm = fmaxf(fmaxf(rowred[0][0][ln], rowred[0][1][ln]),
                     fmaxf(rowred[0][2][ln], rowred[0][3][ln]));
    float sm = 0.f;
#pragma unroll
    for (int tt = 0; tt < 16; ++tt) {
#pragma unroll
        for (int r = 0; r < 4; ++r) {
            float e = __expf(acc_s[tt][r] - gm);
            acc_s[tt][r] = e;
            sm += e;
        }
    }
    sm += __shfl_xor(sm, 16, 64);
    sm += __shfl_xor(sm, 32, 64);
    if (quad == 0) rowred[1][w][ln] = sm;
    __syncthreads();
    float l = rowred[1][0][ln] + rowred[1][1][ln] +
              rowred[1][2][ln] + rowred[1][3][ln];
    float inv = 1.f / l;

    // ---- phase 2.5 + 3: per 64-col sub-chunk, stage fp32 attn in LDS,
    //      wide nontemporal attn stores, MFMA A-frags from the same tile ----
    float* stg = (float*)(smem + (size_t)w * 4352);   // [16][68] fp32
    f32x4 cacc0 = {0.f, 0.f, 0.f, 0.f}, cacc1 = {0.f, 0.f, 0.f, 0.f};
    const size_t vbase = ((size_t)(b * HH + h)) << 15;   // *32*1024
    float* abase = attn + (((size_t)(b * HH + h)) << 20) + (size_t)q0 * SS;
#pragma unroll
    for (int s = 0; s < 4; ++s) {
#pragma unroll
        for (int t = 0; t < 4; ++t) {
            int tt = s * 4 + t;
            float4 o = make_float4(acc_s[tt][0] * inv, acc_s[tt][1] * inv,
                                   acc_s[tt][2] * inv, acc_s[tt][3] * inv);
            *(float4*)&stg[ln * 68 + t * 16 + quad * 4] = o;
        }
        // full-line attn stores: 4 rows x 256B contiguous per instruction
#pragma unroll
        for (int i = 0; i < 4; ++i) {
            int row = i * 4 + quad;
            int c4 = ln * 4;
            f32x4 v = *(f32x4*)&stg[row * 68 + c4];
            __builtin_nontemporal_store(
                v, (f32x4*)&abase[(size_t)row * SS + kw + s * 64 + c4]);
        }
#pragma unroll
        for (int cc = 0; cc < 2; ++cc) {
            int coff = cc * 32 + quad * 8;
            float4 pa = *(float4*)&stg[ln * 68 + coff];
            float4 pb = *(float4*)&stg[ln * 68 + coff + 4];
            bf16x8 af;
            af[0] = f2bf(pa.x); af[1] = f2bf(pa.y);
            af[2] = f2bf(pa.z); af[3] = f2bf(pa.w);
            af[4] = f2bf(pb.x); af[5] = f2bf(pb.y);
            af[6] = f2bf(pb.z); af[7] = f2bf(pb.w);
            int k0 = kw + s * 64 + cc * 32;
            bf16x8 v0 = *(const bf16x8*)(vT + vbase + (((size_t)ln) << 10) + k0 + quad * 8);
            bf16x8 v1 = *(const bf16x8*)(vT + vbase + (((size_t)(16 + ln)) << 10) + k0 + quad * 8);
            cacc0 = __builtin_amdgcn_mfma_f32_16x16x32_bf16(af, v0, cacc0, 0, 0, 0);
            cacc1 = __builtin_amdgcn_mfma_f32_16x16x32_bf16(af, v1, cacc1, 0, 0, 0);
        }
    }

    // cross-wave ctx reduce through dedicated red region (disjoint from stg)
    f32x4* red = (f32x4*)(smem + 17408);
    red[(w * 2 + 0) * 64 + lane] = cacc0;
    red[(w * 2 + 1) * 64 + lane] = cacc1;
    __syncthreads();
    if (tid < 128) {
        int nt = tid >> 6, l2 = tid & 63;
        f32x4 s4 = red[(0 * 2 + nt) * 64 + l2] + red[(1 * 2 + nt) * 64 + l2] +
                   red[(2 * 2 + nt) * 64 + l2] + red[(3 * 2 + nt) * 64 + l2];
        int qd = l2 >> 4, lc = l2 & 15;
#pragma unroll
        for (int r = 0; r < 4; ++r) {
            int qq = qd * 4 + r;
            ctxbf[((size_t)(b * SS + q0 + qq)) * DD + h * DH + nt * 16 + lc] =
                (unsigned short)f2bf(s4[r]);
        }
    }
}

// ---------------------------------------------------------------------------
extern "C" void kernel_launch(void* const* d_in, const int* in_sizes, int n_in,
                              void* d_out, int out_size, void* d_ws, size_t ws_size,
                              hipStream_t stream) {
    const float* query = (const float*)d_in[0];
    const float* key   = (const float*)d_in[1];
    const float* value = (const float*)d_in[2];
    const unsigned char* mask_raw = (const unsigned char*)d_in[3];
    const float* enc   = (const float*)d_in[4];
    const float* Wq    = (const float*)d_in[5];
    const float* bq    = (const float*)d_in[6];
    const float* Wk    = (const float*)d_in[7];
    const float* Wv    = (const float*)d_in[8];
    const float* Wp    = (const float*)d_in[9];
    const float* u_b   = (const float*)d_in[10];
    const float* v_b   = (const float*)d_in[11];
    const float* Wo    = (const float*)d_in[12];
    const float* bo    = (const float*)d_in[13];

    char* wsb = (char*)d_ws;
    float*          qprj = (float*)(wsb + 0);                     // 8 MB fp32
    unsigned short* kprj = (unsigned short*)(wsb + 8388608);      // 4 MB bf16
    unsigned short* vT   = (unsigned short*)(wsb + 12582912);     // 4 MB bf16
    unsigned short* pprj = (unsigned short*)(wsb + 16777216);     // 1 MB bf16
    int*            mnrm = (int*)(wsb + 17825792);                // 16 KB
    unsigned short* ctxbf= (unsigned short*)(wsb + 17842176);     // 4 MB bf16
    // WoT over the dead kbf region (kbf consumed by gemm4 before Wo tconv)
    unsigned short* WoT  = (unsigned short*)(wsb + 22036480);     // 512 KB
    // transients (dead before fused_attn writes ctxbf / WoT tconv)
    unsigned short* qbf  = (unsigned short*)(wsb + 17842176);
    unsigned short* kbf  = (unsigned short*)(wsb + 22036480);
    unsigned short* vbf  = (unsigned short*)(wsb + 26230784);
    unsigned short* ebf  = (unsigned short*)(wsb + 30425088);
    unsigned short* WqT  = (unsigned short*)(wsb + 31473664);
    unsigned short* WkT  = (unsigned short*)(wsb + 31997952);
    unsigned short* WvT  = (unsigned short*)(wsb + 32522240);
    unsigned short* WpT  = (unsigned short*)(wsb + 33046528);

    float* outp = (float*)d_out;                 // (B,S,D)
    float* attn = outp + (size_t)BB * SS * DD;   // (B,H,S,S)

    prep_kernel<<<6913, 256, 0, stream>>>(
        query, key, value, enc, Wq, Wk, Wv, Wp, mask_raw,
        qbf, kbf, vbf, ebf, WqT, WkT, WvT, WpT, mnrm);

    gemm4_kernel<<<416, 256, 0, stream>>>(
        qbf, WqT, bq, qprj, kbf, WkT, kprj, vbf, WvT, vT, ebf, WpT, pprj);

    tconv_kernel<<<dim3(8, 8), 256, 0, stream>>>(Wo, WoT);

    fused_attn_kernel<<<dim3(SS / 16, HH, BB), 256, 0, stream>>>(
        qprj, kprj, pprj, vT, u_b, v_b, mnrm, attn, ctxbf);

    gemm_out_kernel<<<128, 256, 0, stream>>>(ctxbf, WoT, bo, outp);
}